// Round 5
// baseline (270.666 us; speedup 1.0000x reference)
//
#include <hip/hip_runtime.h>
#include <math.h>

#define ALPHA 0.12f
#define BETA  0.88f
#define OMEGA 6.0f
#define TWO_PI 6.28318530717958647692f

constexpr int Bn   = 4;
constexpr int Tn   = 4096;
constexpr int Dn   = 2048;
constexpr int HALF = Dn / 2;      // 1024
constexpr int L    = 32;          // output chunk length
constexpr int NC   = Tn / L;      // 128 chunks
constexpr int WU   = 64;          // warm-up steps (2 chunks)

typedef float fx2 __attribute__((ext_vector_type(2)));

// ---------------------------------------------------------------------------
// Single fused kernel, latency-hiding version.
// Grid: Bn × NC × 2 = 1024 blocks (4 blocks/CU = 4 waves/SIMD, 4× round 4's
// occupancy). Block (b, c, h): 256 threads, thread owns one fx2 pair-lane
// (a[d..d+1], b[d..d+1]) with d = 2*(h*256 + tid).
//
// Carry-in via truncated warm-up of WU=64 steps over chunks c-2, c-1:
//   c*L <= WU (c in {0,1,2}): warm-up starts at t=0 with mem_state init
//     -> EXACT full history.
//   c >= 3: zero init at t = c*L-64; truncation error beta^64 = 2.8e-4,
//     damped by sigmoid(-2)=0.119 at the output -> ~1e-4 absolute, far
//     below tolerance.
// x is read ~3x logically but chunks are re-touched near-simultaneously by
// neighboring blocks -> extra reads hit L2/L3 (round-4 counters confirmed:
// FETCH_SIZE stayed at 130 MB with 2x logical reads). Theta (32 rows) is
// computed inline into LDS, hidden under the warm-up loads.
// ---------------------------------------------------------------------------
__global__ __launch_bounds__(256) void k_fused(
        const float* __restrict__ x,
        const float* __restrict__ gate,
        const float* __restrict__ input_scale,
        const float* __restrict__ mem_state,
        const int*   __restrict__ step_idx,
        float* __restrict__ out) {
    int tid = threadIdx.x;                    // 0..255
    int h   = blockIdx.x & 1;                 // D-half-split
    int c   = (blockIdx.x >> 1) & (NC - 1);   // 0..127
    int b   = blockIdx.x >> 8;                // 0..3

    const float sc  = ALPHA * (*input_scale);
    const float sig = 1.0f / (1.0f + expf(-(*gate)));

    int d  = 2 * (h * 256 + tid);             // pair index 0..1022 (even)
    int t0 = c * L;                           // output chunk start

    // theta table for this chunk's 32 rows -> LDS (latency overlaps warm-up)
    __shared__ float cs[L];
    __shared__ float ss[L];
    if (tid < L) {
        float tg = (float)(t0 + tid + 1 + *step_idx);
        float theta = fmodf(OMEGA * log1pf(tg), TWO_PI);
        cs[tid] = cosf(theta);
        ss[tid] = sinf(theta);
    }

    // ---- carry-in reconstruction (warm-up scan, no stores) ----
    fx2 ma, mb;
    if (t0 <= WU) {   // full history covered: exact init from mem_state
        ma = *(const fx2*)(mem_state + d);
        mb = *(const fx2*)(mem_state + HALF + d);
    } else {          // truncated history: beta^64 ~ 2.8e-4
        ma = (fx2)(0.0f);
        mb = (fx2)(0.0f);
    }
    int ws   = t0 - WU; if (ws < 0) ws = 0;
    int wlen = t0 - ws;                       // 0, 32, or 64
    const float* wrow = x + ((size_t)b * Tn + (size_t)ws) * Dn;
#pragma unroll 8
    for (int i = 0; i < wlen; ++i) {
        fx2 va = *(const fx2*)(wrow + d);
        fx2 vb = *(const fx2*)(wrow + HALF + d);
        ma = BETA * ma + sc * va;
        mb = BETA * mb + sc * vb;
        wrow += Dn;
    }
    __syncthreads();   // cs/ss ready (all 256 threads reach this)

    // ---- output pass over chunk c ----
    const float* xrow = x   + ((size_t)b * Tn + (size_t)t0) * Dn;
    float*       orow = out + ((size_t)b * Tn + (size_t)t0) * Dn;
#pragma unroll 4
    for (int i = 0; i < L; ++i) {
        fx2 va = *(const fx2*)(xrow + d);
        fx2 vb = *(const fx2*)(xrow + HALF + d);
        ma = BETA * ma + sc * va;
        mb = BETA * mb + sc * vb;
        float cth = cs[i];
        float sth = ss[i];
        fx2 ra = va + sig * (ma * cth - mb * sth);
        fx2 rb = vb + sig * (ma * sth + mb * cth);
        __builtin_nontemporal_store(ra, (fx2*)(orow + d));
        __builtin_nontemporal_store(rb, (fx2*)(orow + HALF + d));
        xrow += Dn;
        orow += Dn;
    }
}

// ---------------------------------------------------------------------------
extern "C" void kernel_launch(void* const* d_in, const int* in_sizes, int n_in,
                              void* d_out, int out_size, void* d_ws, size_t ws_size,
                              hipStream_t stream) {
    const float* x           = (const float*)d_in[0];
    const float* gate        = (const float*)d_in[1];
    const float* input_scale = (const float*)d_in[2];
    const float* mem_state   = (const float*)d_in[3];
    const int*   step_idx    = (const int*)d_in[4];
    float* out = (float*)d_out;

    (void)d_ws; (void)ws_size;  // workspace not needed

    k_fused<<<Bn * NC * 2, 256, 0, stream>>>(x, gate, input_scale, mem_state,
                                             step_idx, out);
}